// Round 6
// baseline (4920.007 us; speedup 1.0000x reference)
//
#include <hip/hip_runtime.h>
#include <math.h>

#define HW 320
#define IMGSZ (HW*HW)
#define NB 4

__device__ __forceinline__ float4 ld4(const float* p){ return *reinterpret_cast<const float4*>(p); }

// ---------------------------------------------------------------------------
// adconv metadata: indexs=argmax(para,1); perm=stable argsort(indexs);
// mul[t]=sum(para max | idx==t)/max(cnt,1)+1. Slot k: src=perm[k],
// d=indexs[src]+1, scale=mul[indexs[src]].
// ---------------------------------------------------------------------------
__global__ void meta_kernel(const float* p0,const float* p1,const float* p2,
                            const float* p3,const float* p4,const float* p5,
                            int* msrc,int* md,float* mscale){
  if (threadIdx.x != 0) return;
  int set = blockIdx.x;
  const float* ps[6] = {p0,p1,p2,p3,p4,p5};
  const int Ts[6] = {1,3,1,3,1,3};   // c1f, c2f, c1b, c2b, c1g, c2g
  const float* para = ps[set];
  int T = Ts[set];
  int idx[32]; float mx[32];
  for (int c=0;c<32;c++){
    int best=0; float bv=para[c*T];
    for (int t=1;t<T;t++){ float v=para[c*T+t]; if (v>bv){bv=v;best=t;} }
    idx[c]=best; mx[c]=bv;
  }
  float sum[3]={0.f,0.f,0.f}; int cnt[3]={0,0,0};
  for (int c=0;c<32;c++){ sum[idx[c]] += mx[c]; cnt[idx[c]]++; }
  float mul[3];
  for (int t=0;t<3;t++) mul[t] = sum[t]/fmaxf((float)cnt[t],1.f)+1.f;
  int off[3]; off[0]=0; off[1]=cnt[0]; off[2]=cnt[0]+cnt[1];
  int perm[32];
  for (int c=0;c<32;c++) perm[off[idx[c]]++] = c;   // stable counting sort
  for (int k=0;k<32;k++){
    int s = perm[k];
    msrc[set*32+k]=s; md[set*32+k]=idx[s]+1; mscale[set*32+k]=mul[idx[s]];
  }
}

// u = x + xi*(x - xprev)
__global__ void ew_u(const float* __restrict__ x, const float* __restrict__ xprev,
                     const float* __restrict__ t_p, float* __restrict__ u, int n4){
  int i = blockIdx.x*blockDim.x + threadIdx.x;
  if (i >= n4) return;
  float t = *t_p;
  float tplus = (1.f + sqrtf(1.f + 4.f*t*t)) * 0.5f;
  float xi = (t - 1.f)/tplus;
  float4 xv = ld4(x + 4*i); float4 pv = ld4(xprev + 4*i);
  float4 r;
  r.x = xv.x + xi*(xv.x-pv.x);
  r.y = xv.y + xi*(xv.y-pv.y);
  r.z = xv.z + xi*(xv.z-pv.z);
  r.w = xv.w + xi*(xv.w-pv.w);
  *reinterpret_cast<float4*>(u + 4*i) = r;
}

// phi[b,c,blk,m] (per-channel!)   grid(100,3,4) x 256
__global__ void phi_fwd(const float* __restrict__ u, const float* __restrict__ PhiW,
                        float* __restrict__ phi){
  int blk = blockIdx.x, c = blockIdx.y, b = blockIdx.z;
  int bh = blk/10, bw = blk%10;
  __shared__ float ub[1024];
  int tid = threadIdx.x;
  {
    int i = tid >> 3, j4 = (tid & 7) << 2;
    const float* src = u + (size_t)((b*3 + c)*HW + bh*32 + i)*HW + bw*32 + j4;
    *reinterpret_cast<float4*>(ub + i*32 + j4) = ld4(src);
  }
  __syncthreads();
  int m = tid;
  const float* wp = PhiW + (size_t)(m*3 + c)*1024;
  float acc = 0.f;
  #pragma unroll 8
  for (int q = 0; q < 1024; q += 4){
    float4 w = ld4(wp + q);
    float4 uv = *reinterpret_cast<const float4*>(ub + q);
    acc += w.x*uv.x + w.y*uv.y + w.z*uv.z + w.w*uv.w;
  }
  phi[((size_t)(b*3 + c)*100 + blk)*256 + m] = acc;
}

// x_input = u - lam*phitphi + lam*PhiTb   grid(100,3,4) x 256
__global__ void phit_zeta(const float* __restrict__ phi, const float* __restrict__ PhiTW,
                          const float* __restrict__ u, const float* __restrict__ PhiTb,
                          const float* __restrict__ lam_p, float* __restrict__ x_input){
  int blk = blockIdx.x, c = blockIdx.y, b = blockIdx.z;
  int bh = blk/10, bw = blk%10;
  __shared__ float pb[256];
  int tid = threadIdx.x;
  pb[tid] = phi[((size_t)(b*3 + c)*100 + blk)*256 + tid];
  __syncthreads();
  float lam = *lam_p;
  for (int nn = tid; nn < 1024; nn += 256){
    const float* wp = PhiTW + (size_t)(c*1024 + nn)*256;
    float acc = 0.f;
    #pragma unroll 8
    for (int q=0;q<256;q+=4){
      float4 w = ld4(wp+q);
      float4 pv = *reinterpret_cast<const float4*>(pb+q);
      acc += w.x*pv.x + w.y*pv.y + w.z*pv.z + w.w*pv.w;
    }
    int i = nn>>5, j = nn&31;
    size_t g = (size_t)((b*3+c)*HW + bh*32+i)*HW + bw*32 + j;
    x_input[g] = u[g] - lam*acc + lam*PhiTb[g];
  }
}

// ---------------------------------------------------------------------------
// 3x3 conv, "same", dilation D (template). Block (16,16) = 64x32 px tile,
// thread tile 4x2 px, NK=2 output-channel slots.
// REGISTER LESSON (R3-R5): demand must fit under ~64 VGPR or the allocator
// rematerializes weights from LDS inside the ic loop (R5: VGPR=56, VALU 16%).
// NK=2: acc 16 + wk 18 + window 12 + addr ~15 = ~60 regs -> 8 waves/SIMD.
// Input re-read by 16 kgroups is L2-absorbed (kgroup = blockIdx.x fastest;
// R5 measured FETCH ~= ideal with this ordering).
// Branch-free FMA core: inactive slots get zeroed weights in LDS.
// ITRANS: 0 none,1 relu,2 soft-thr. EPI: 0 none,1 relu,2 merge,3 sub.
// ---------------------------------------------------------------------------
template<int CIN, int COUT, int NK, int D, int ITRANS, int EPI>
__global__ __launch_bounds__(256, 6)
void conv3x3(const float* __restrict__ in, const float* __restrict__ wts,
             float* __restrict__ out,
             const int* __restrict__ msrc, const int* __restrict__ md,
             const float* __restrict__ mscale,
             const float* __restrict__ thr_p,
             const float* __restrict__ epi_ptr,
             const float* __restrict__ ms_p){
  const int kg = blockIdx.x;
  const int b  = blockIdx.z;
  const int k0 = kg*NK;
  const int tile = blockIdx.y;     // 50 tiles: 5 in x, 10 in y

  bool act[NK]; float scl[NK]; bool any = false;
  #pragma unroll
  for (int kk=0;kk<NK;kk++){
    int k = k0+kk;
    int d = md ? md[k] : 1;
    act[kk] = (d==D);
    scl[kk] = mscale ? mscale[k] : 1.f;
    any = any || act[kk];
  }
  if (!any) return;   // wave-uniform

  __shared__ float wsm[NK*CIN*12];   // 9 taps padded to 12 for float4 reads
  int tid = threadIdx.y*16 + threadIdx.x;
  for (int q = tid; q < NK*CIN*9; q += 256){
    int kk = q/(CIN*9); int rem = q - kk*(CIN*9); int ic = rem/9; int t = rem - ic*9;
    int src = msrc ? msrc[k0+kk] : (k0+kk);
    wsm[(kk*CIN+ic)*12 + t] = act[kk] ? wts[(size_t)src*(CIN*9) + rem] : 0.f;
  }
  __syncthreads();

  const int x0 = (tile%5)*64 + threadIdx.x*4;
  const int y0 = (tile/5)*32 + threadIdx.y*2;
  const float thr = (ITRANS==2) ? *thr_p : 0.f;
  float acc[NK][2][4] = {};

  for (int ic=0; ic<CIN; ++ic){
    const float* ip = in + (size_t)(b*CIN+ic)*IMGSZ;
    float wk[NK][9];
    #pragma unroll
    for (int kk=0;kk<NK;kk++){
      const float* wp = &wsm[(kk*CIN+ic)*12];
      float4 a = *reinterpret_cast<const float4*>(wp);
      float4 bb= *reinterpret_cast<const float4*>(wp+4);
      float4 cc= *reinterpret_cast<const float4*>(wp+8);
      wk[kk][0]=a.x; wk[kk][1]=a.y; wk[kk][2]=a.z; wk[kk][3]=a.w;
      wk[kk][4]=bb.x; wk[kk][5]=bb.y; wk[kk][6]=bb.z; wk[kk][7]=bb.w;
      wk[kk][8]=cc.x;
    }
    #pragma unroll
    for (int r=0; r<2+2*D; ++r){
      int yr = y0 - D + r;
      if (yr < 0 || yr >= HW) continue;
      const float* rp = ip + (size_t)yr*HW;
      float4 v0 = (x0 >= 4)    ? ld4(rp + x0-4) : float4{0.f,0.f,0.f,0.f};
      float4 v1 = ld4(rp + x0);
      float4 v2 = (x0+4 < HW)  ? ld4(rp + x0+4) : float4{0.f,0.f,0.f,0.f};
      float w12[12] = {v0.x,v0.y,v0.z,v0.w, v1.x,v1.y,v1.z,v1.w, v2.x,v2.y,v2.z,v2.w};
      if (ITRANS==1){
        #pragma unroll
        for (int q=0;q<12;q++) w12[q] = fmaxf(w12[q],0.f);
      } else if (ITRANS==2){
        #pragma unroll
        for (int q=0;q<12;q++){
          float a = fabsf(w12[q]) - thr;
          w12[q] = (a > 0.f) ? copysignf(a, w12[q]) : 0.f;
        }
      }
      #pragma unroll
      for (int kk=0;kk<NK;kk++){
        #pragma unroll
        for (int ky=0; ky<3; ++ky){
          int j = r - ky*D;
          if (j >= 0 && j < 2){
            #pragma unroll
            for (int p=0;p<4;p++){
              #pragma unroll
              for (int kx=0;kx<3;kx++)
                acc[kk][j][p] += wk[kk][ky*3+kx] * w12[4 + p + (kx-1)*D];
            }
          }
        }
      }
    }
  }

  float ms = (EPI==2) ? *ms_p : 0.f;
  #pragma unroll
  for (int kk=0;kk<NK;kk++){
    if (!act[kk]) continue;   // store only live slots
    int k = k0+kk;
    #pragma unroll
    for (int j=0;j<2;j++){
      size_t oidx = ((size_t)(b*COUT + k)*HW + (y0+j))*HW + x0;
      float4 o;
      float* op = reinterpret_cast<float*>(&o);
      float4 e;
      if (EPI==2 || EPI==3) e = ld4(epi_ptr + oidx);
      #pragma unroll
      for (int p=0;p<4;p++){
        float v = acc[kk][j][p]*scl[kk];
        if (EPI==1) v = fmaxf(v,0.f);
        else if (EPI==2) v = reinterpret_cast<float*>(&e)[p] + ms*v;
        else if (EPI==3) v = v - reinterpret_cast<float*>(&e)[p];
        op[p] = v;
      }
      *reinterpret_cast<float4*>(out + oidx) = o;
    }
  }
}

// ---------------------------------------------------------------------------
extern "C" void kernel_launch(void* const* d_in, const int* in_sizes, int n_in,
                              void* d_out, int out_size, void* d_ws, size_t ws_size,
                              hipStream_t stream) {
  const float* xprev = (const float*)d_in[0];
  const float* x     = (const float*)d_in[1];
  const float* PhiW  = (const float*)d_in[2];
  const float* PhiTW = (const float*)d_in[3];
  const float* PhiTb = (const float*)d_in[4];
  const float* lam   = (const float*)d_in[5];
  const float* sthr  = (const float*)d_in[6];
  const float* t_p   = (const float*)d_in[7];
  const float* mrg   = (const float*)d_in[8];
  const float* convD = (const float*)d_in[9];
  const float* conv3G= (const float*)d_in[10];
  const float* c1f_w=(const float*)d_in[11]; const float* c1f_p=(const float*)d_in[12];
  const float* c2f_w=(const float*)d_in[13]; const float* c2f_p=(const float*)d_in[14];
  const float* c1b_w=(const float*)d_in[15]; const float* c1b_p=(const float*)d_in[16];
  const float* c2b_w=(const float*)d_in[17]; const float* c2b_p=(const float*)d_in[18];
  const float* c1g_w=(const float*)d_in[19]; const float* c1g_p=(const float*)d_in[20];
  const float* c2g_w=(const float*)d_in[21]; const float* c2g_p=(const float*)d_in[22];

  char* ws = (char*)d_ws;
  const size_t BIG = (size_t)NB*32*IMGSZ*sizeof(float);     // 52,428,800
  float* A       = (float*)(ws);                // x_D (kept for symloss)
  float* Bb      = (float*)(ws + BIG);
  float* Cc      = (float*)(ws + 2*BIG);        // x_forward (kept)
  float* Dd      = (float*)(ws + 3*BIG);
  float* x_input = (float*)(ws + 4*BIG);                      // 4.9 MB
  float* u       = (float*)(ws + 4*BIG + 4915200);            // 4.9 MB
  float* phi     = (float*)(ws + 4*BIG + 2*4915200);          // 4.9 MB (per-channel)
  char*  mbase   = ws + 4*BIG + 3*4915200;
  int*   msrc    = (int*)(mbase);
  int*   md      = (int*)(mbase + 6*32*4);
  float* mscale  = (float*)(mbase + 2*6*32*4);

  float* out0 = (float*)d_out;
  float* out1 = out0 + (size_t)NB*3*IMGSZ;

  dim3 cb(16,16);
  dim3 g32(16,50,NB);   // 32 out channels / NK=2, 50 tiles of 64x32
  dim3 g3(3,50,NB);     // 3 out channels, NK=1

  // meta sets: 0=c1f 1=c2f 2=c1b 3=c2b 4=c1g 5=c2g
  meta_kernel<<<6, 64, 0, stream>>>(c1f_p,c2f_p,c1b_p,c2b_p,c1g_p,c2g_p, msrc,md,mscale);

  ew_u<<<1200, 256, 0, stream>>>(x, xprev, t_p, u, 307200);
  phi_fwd<<<dim3(100,3,NB), 256, 0, stream>>>(u, PhiW, phi);
  phit_zeta<<<dim3(100,3,NB), 256, 0, stream>>>(phi, PhiTW, u, PhiTb, lam, x_input);

  // x_D = conv_D(x_input)
  conv3x3<3,32,2,1,0,0><<<g32,cb,0,stream>>>(x_input, convD, A, nullptr,nullptr,nullptr, nullptr,nullptr,nullptr);
  // h1 = relu(adconv(x_D, c1f))
  conv3x3<32,32,2,1,0,1><<<g32,cb,0,stream>>>(A, c1f_w, Bb, msrc, md, mscale, nullptr,nullptr,nullptr);
  // x_forward = adconv(h1, c2f)
  conv3x3<32,32,2,1,0,0><<<g32,cb,0,stream>>>(Bb, c2f_w, Cc, msrc+32, md+32, mscale+32, nullptr,nullptr,nullptr);
  conv3x3<32,32,2,2,0,0><<<g32,cb,0,stream>>>(Bb, c2f_w, Cc, msrc+32, md+32, mscale+32, nullptr,nullptr,nullptr);
  conv3x3<32,32,2,3,0,0><<<g32,cb,0,stream>>>(Bb, c2f_w, Cc, msrc+32, md+32, mscale+32, nullptr,nullptr,nullptr);
  // h2 = relu(adconv(soft(x_forward), c1f))
  conv3x3<32,32,2,1,2,1><<<g32,cb,0,stream>>>(Cc, c1f_w, Dd, msrc, md, mscale, sthr,nullptr,nullptr);
  // x_backward = adconv(h2, c2b)
  conv3x3<32,32,2,1,0,0><<<g32,cb,0,stream>>>(Dd, c2b_w, Bb, msrc+96, md+96, mscale+96, nullptr,nullptr,nullptr);
  conv3x3<32,32,2,2,0,0><<<g32,cb,0,stream>>>(Dd, c2b_w, Bb, msrc+96, md+96, mscale+96, nullptr,nullptr,nullptr);
  conv3x3<32,32,2,3,0,0><<<g32,cb,0,stream>>>(Dd, c2b_w, Bb, msrc+96, md+96, mscale+96, nullptr,nullptr,nullptr);
  // h3 = adconv(relu(x_backward), c1g)
  conv3x3<32,32,2,1,1,0><<<g32,cb,0,stream>>>(Bb, c1g_w, Dd, msrc+128, md+128, mscale+128, nullptr,nullptr,nullptr);
  // h4 = adconv(relu(h3), c2g)
  conv3x3<32,32,2,1,1,0><<<g32,cb,0,stream>>>(Dd, c2g_w, Bb, msrc+160, md+160, mscale+160, nullptr,nullptr,nullptr);
  conv3x3<32,32,2,2,1,0><<<g32,cb,0,stream>>>(Dd, c2g_w, Bb, msrc+160, md+160, mscale+160, nullptr,nullptr,nullptr);
  conv3x3<32,32,2,3,1,0><<<g32,cb,0,stream>>>(Dd, c2g_w, Bb, msrc+160, md+160, mscale+160, nullptr,nullptr,nullptr);
  // x_pred = x_input + mergeScale * conv3_G(h4)  -> out0
  conv3x3<32,3,1,1,0,2><<<g3,cb,0,stream>>>(Bb, conv3G, out0, nullptr,nullptr,nullptr, nullptr, x_input, mrg);
  // h5 = relu(adconv(x_forward, c1b))
  conv3x3<32,32,2,1,0,1><<<g32,cb,0,stream>>>(Cc, c1b_w, Dd, msrc+64, md+64, mscale+64, nullptr,nullptr,nullptr);
  // symloss = adconv(h5, c2b) - x_D  -> out1
  conv3x3<32,32,2,1,0,3><<<g32,cb,0,stream>>>(Dd, c2b_w, out1, msrc+96, md+96, mscale+96, nullptr, A, nullptr);
  conv3x3<32,32,2,2,0,3><<<g32,cb,0,stream>>>(Dd, c2b_w, out1, msrc+96, md+96, mscale+96, nullptr, A, nullptr);
  conv3x3<32,32,2,3,0,3><<<g32,cb,0,stream>>>(Dd, c2b_w, out1, msrc+96, md+96, mscale+96, nullptr, A, nullptr);
}

// Round 7
// 749.284 us; speedup vs baseline: 6.5663x; 6.5663x over previous
//
#include <hip/hip_runtime.h>
#include <math.h>

#define HW 320
#define IMGSZ (HW*HW)
#define NB 4

typedef __bf16 bf16x8 __attribute__((ext_vector_type(8)));
typedef float  f32x4  __attribute__((ext_vector_type(4)));

__device__ __forceinline__ float4 ld4(const float* p){ return *reinterpret_cast<const float4*>(p); }

__device__ __forceinline__ unsigned short f2b(float f){
  unsigned u = __float_as_uint(f);
  unsigned r = (u + 0x7fffu + ((u>>16)&1u)) >> 16;
  return (unsigned short)r;
}

// ---------------------------------------------------------------------------
// adconv metadata + per-set dilation presence bitmask
// ---------------------------------------------------------------------------
__global__ void meta_kernel(const float* p0,const float* p1,const float* p2,
                            const float* p3,const float* p4,const float* p5,
                            int* msrc,int* md,float* mscale,int* pres){
  if (threadIdx.x != 0) return;
  int set = blockIdx.x;
  const float* ps[6] = {p0,p1,p2,p3,p4,p5};
  const int Ts[6] = {1,3,1,3,1,3};   // c1f, c2f, c1b, c2b, c1g, c2g
  const float* para = ps[set];
  int T = Ts[set];
  int idx[32]; float mx[32];
  for (int c=0;c<32;c++){
    int best=0; float bv=para[c*T];
    for (int t=1;t<T;t++){ float v=para[c*T+t]; if (v>bv){bv=v;best=t;} }
    idx[c]=best; mx[c]=bv;
  }
  float sum[3]={0.f,0.f,0.f}; int cnt[3]={0,0,0};
  for (int c=0;c<32;c++){ sum[idx[c]] += mx[c]; cnt[idx[c]]++; }
  float mul[3];
  for (int t=0;t<3;t++) mul[t] = sum[t]/fmaxf((float)cnt[t],1.f)+1.f;
  int off[3]; off[0]=0; off[1]=cnt[0]; off[2]=cnt[0]+cnt[1];
  int perm[32];
  for (int c=0;c<32;c++) perm[off[idx[c]]++] = c;   // stable counting sort
  int pb = 0;
  for (int k=0;k<32;k++){
    int s = perm[k];
    msrc[set*32+k]=s; md[set*32+k]=idx[s]+1; mscale[set*32+k]=mul[idx[s]];
    pb |= 1 << (idx[s]+1);
  }
  pres[set] = pb;
}

// u = x + xi*(x - xprev)
__global__ void ew_u(const float* __restrict__ x, const float* __restrict__ xprev,
                     const float* __restrict__ t_p, float* __restrict__ u, int n4){
  int i = blockIdx.x*blockDim.x + threadIdx.x;
  if (i >= n4) return;
  float t = *t_p;
  float tplus = (1.f + sqrtf(1.f + 4.f*t*t)) * 0.5f;
  float xi = (t - 1.f)/tplus;
  float4 xv = ld4(x + 4*i); float4 pv = ld4(xprev + 4*i);
  float4 r;
  r.x = xv.x + xi*(xv.x-pv.x);
  r.y = xv.y + xi*(xv.y-pv.y);
  r.z = xv.z + xi*(xv.z-pv.z);
  r.w = xv.w + xi*(xv.w-pv.w);
  *reinterpret_cast<float4*>(u + 4*i) = r;
}

// phi[b,c,blk,m] (per-channel)   grid(100,3,4) x 256
__global__ void phi_fwd(const float* __restrict__ u, const float* __restrict__ PhiW,
                        float* __restrict__ phi){
  int blk = blockIdx.x, c = blockIdx.y, b = blockIdx.z;
  int bh = blk/10, bw = blk%10;
  __shared__ float ub[1024];
  int tid = threadIdx.x;
  {
    int i = tid >> 3, j4 = (tid & 7) << 2;
    const float* src = u + (size_t)((b*3 + c)*HW + bh*32 + i)*HW + bw*32 + j4;
    *reinterpret_cast<float4*>(ub + i*32 + j4) = ld4(src);
  }
  __syncthreads();
  int m = tid;
  const float* wp = PhiW + (size_t)(m*3 + c)*1024;
  float acc = 0.f;
  #pragma unroll 8
  for (int q = 0; q < 1024; q += 4){
    float4 w = ld4(wp + q);
    float4 uv = *reinterpret_cast<const float4*>(ub + q);
    acc += w.x*uv.x + w.y*uv.y + w.z*uv.z + w.w*uv.w;
  }
  phi[((size_t)(b*3 + c)*100 + blk)*256 + m] = acc;
}

// x_input = u - lam*phitphi + lam*PhiTb   grid(100,3,4) x 256
__global__ void phit_zeta(const float* __restrict__ phi, const float* __restrict__ PhiTW,
                          const float* __restrict__ u, const float* __restrict__ PhiTb,
                          const float* __restrict__ lam_p, float* __restrict__ x_input){
  int blk = blockIdx.x, c = blockIdx.y, b = blockIdx.z;
  int bh = blk/10, bw = blk%10;
  __shared__ float pb[256];
  int tid = threadIdx.x;
  pb[tid] = phi[((size_t)(b*3 + c)*100 + blk)*256 + tid];
  __syncthreads();
  float lam = *lam_p;
  for (int nn = tid; nn < 1024; nn += 256){
    const float* wp = PhiTW + (size_t)(c*1024 + nn)*256;
    float acc = 0.f;
    #pragma unroll 8
    for (int q=0;q<256;q+=4){
      float4 w = ld4(wp+q);
      float4 pv = *reinterpret_cast<const float4*>(pb+q);
      acc += w.x*pv.x + w.y*pv.y + w.z*pv.z + w.w*pv.w;
    }
    int i = nn>>5, j = nn&31;
    size_t g = (size_t)((b*3+c)*HW + bh*32+i)*HW + bw*32 + j;
    x_input[g] = u[g] - lam*acc + lam*PhiTb[g];
  }
}

// ---------------------------------------------------------------------------
// convD: direct fp32 3x3 conv (CIN=3 -> 32oc), NCHW fp32 out. (proven R6 code)
// ---------------------------------------------------------------------------
template<int CIN, int COUT, int NK, int D>
__global__ __launch_bounds__(256)
void conv_direct(const float* __restrict__ in, const float* __restrict__ wts,
                 float* __restrict__ out){
  const int kg = blockIdx.x;
  const int b  = blockIdx.z;
  const int k0 = kg*NK;
  const int tile = blockIdx.y;     // 50 tiles: 5 x, 10 y

  __shared__ float wsm[NK*CIN*12];
  int tid = threadIdx.y*16 + threadIdx.x;
  for (int q = tid; q < NK*CIN*9; q += 256){
    int kk = q/(CIN*9); int rem = q - kk*(CIN*9);
    wsm[(kk*CIN + rem/9)*12 + rem%9] = wts[(size_t)(k0+kk)*(CIN*9) + rem];
  }
  __syncthreads();

  const int x0 = (tile%5)*64 + threadIdx.x*4;
  const int y0 = (tile/5)*32 + threadIdx.y*2;
  float acc[NK][2][4] = {};

  for (int ic=0; ic<CIN; ++ic){
    const float* ip = in + (size_t)(b*CIN+ic)*IMGSZ;
    float wk[NK][9];
    #pragma unroll
    for (int kk=0;kk<NK;kk++){
      #pragma unroll
      for (int q=0;q<9;q++) wk[kk][q] = wsm[(kk*CIN+ic)*12+q];
    }
    #pragma unroll
    for (int r=0; r<2+2*D; ++r){
      int yr = y0 - D + r;
      if (yr < 0 || yr >= HW) continue;
      const float* rp = ip + (size_t)yr*HW;
      float4 v0 = (x0 >= 4)   ? ld4(rp + x0-4) : float4{0.f,0.f,0.f,0.f};
      float4 v1 = ld4(rp + x0);
      float4 v2 = (x0+4 < HW) ? ld4(rp + x0+4) : float4{0.f,0.f,0.f,0.f};
      float w12[12] = {v0.x,v0.y,v0.z,v0.w, v1.x,v1.y,v1.z,v1.w, v2.x,v2.y,v2.z,v2.w};
      #pragma unroll
      for (int kk=0;kk<NK;kk++){
        #pragma unroll
        for (int ky=0; ky<3; ++ky){
          int j = r - ky*D;
          if (j >= 0 && j < 2){
            #pragma unroll
            for (int p=0;p<4;p++){
              #pragma unroll
              for (int kx=0;kx<3;kx++)
                acc[kk][j][p] += wk[kk][ky*3+kx] * w12[4 + p + (kx-1)*D];
            }
          }
        }
      }
    }
  }
  #pragma unroll
  for (int kk=0;kk<NK;kk++){
    int k = k0+kk;
    #pragma unroll
    for (int j=0;j<2;j++){
      size_t oidx = ((size_t)(b*COUT + k)*HW + (y0+j))*HW + x0;
      float4 o; float* op = (float*)&o;
      #pragma unroll
      for (int p=0;p<4;p++) op[p] = acc[kk][j][p];
      *reinterpret_cast<float4*>(out + oidx) = o;
    }
  }
}

// ---------------------------------------------------------------------------
// NCHW fp32 (32ch) -> blocked bf16 [b][g=4][y][x][8ch]
// ---------------------------------------------------------------------------
__global__ void cvt_blocked(const float* __restrict__ src, uint4* __restrict__ dst){
  int idx = blockIdx.x*256 + threadIdx.x;           // 4*4*320*80
  if (idx >= 4*4*320*80) return;
  int x4 = idx % 80; int t = idx / 80;
  int y = t % 320; t /= 320;
  int g = t % 4; int b = t / 4;
  int x = x4*4;
  float vals[8][4];
  #pragma unroll
  for (int c=0;c<8;c++){
    float4 v = ld4(src + (((size_t)(b*32 + g*8 + c)*HW + y)*HW + x));
    vals[c][0]=v.x; vals[c][1]=v.y; vals[c][2]=v.z; vals[c][3]=v.w;
  }
  #pragma unroll
  for (int p=0;p<4;p++){
    uint4 o;
    unsigned* ow = (unsigned*)&o;
    #pragma unroll
    for (int c=0;c<4;c++)
      ow[c] = (unsigned)f2b(vals[2*c][p]) | ((unsigned)f2b(vals[2*c+1][p])<<16);
    dst[(((size_t)(b*4+g)*HW + y)*HW + x + p)] = o;
  }
}

// ---------------------------------------------------------------------------
// Weight packing: B-fragment order, perm+scale folded, off-class zeroed.
// slot layout: [slot][(h*9+t)*64+lane] -> 8 bf16 (=1 uint4).
// B[k][n]: n = lane&15 (oc within half h), k = (lane>>4)*8 + j (ic).
// ---------------------------------------------------------------------------
__global__ void pack_w(const float* w0,const float* w1,const float* w2,
                       const float* w3,const float* w4,const float* w5,
                       const float* w6,
                       const int* msrc,const int* md,const float* mscale,
                       uint4* __restrict__ wp){
  const float* wsel[7] = {w0,w1,w2,w3,w4,w5,w6};
  const int set_of[13]  = {0,1,1,1,2,3,3,3,4,5,5,5,6};
  const int cls_of[13]  = {1,1,2,3,1,1,2,3,1,1,2,3,1};
  int slot = blockIdx.x;
  int set = set_of[slot], cls = cls_of[slot];
  const float* W = wsel[set];
  unsigned short* out = (unsigned short*)(wp + (size_t)slot*1152);
  for (int v = threadIdx.x; v < 9216; v += 256){
    int j = v & 7;
    int lane = (v >> 3) & 63;
    int rest = v >> 9;           // h*9+t
    int t = rest % 9, h = rest / 9;
    int ocl = lane & 15, q = lane >> 4;
    int oc = h*16 + ocl;
    int ic = q*8 + j;
    float val = 0.f;
    if (set == 6){
      if (oc < 3) val = W[(size_t)oc*(32*9) + ic*9 + t];
    } else {
      if (md[set*32+oc] == cls){
        int src = msrc[set*32+oc];
        val = W[(size_t)src*(32*9) + ic*9 + t] * mscale[set*32+oc];
      }
    }
    out[v] = f2b(val);
  }
}

// ---------------------------------------------------------------------------
// MFMA conv. Block 256thr=4 waves; block tile 32x(16 rows); wave: 4 rows x 32.
// LDS: input tile channel-group blocked, halo H. A-frag = dense ds_read_b128.
// B-frag from packed global weights. NPASS: dilation classes (runtime loop).
// NH: oc halves (2 => 32 oc; 1 => 16). ITRANS: 0 none 1 relu 2 soft-thr.
// EPI: 0 none / 1 relu  (blocked bf16 out via LDS transpose)
//      2 merge: out0 fp32 = epi + ms*acc (oc<3 only)
//      3 sub:   out1 fp32 = acc - epi
// ---------------------------------------------------------------------------
template<int H, int NPASS, int NH, int ITRANS, int EPI>
__global__ __launch_bounds__(256, 2)
void mfma_conv(const uint4* __restrict__ inb, const uint4* __restrict__ wp,
               void* __restrict__ outp,
               const int* __restrict__ pres_p, int set,
               const float* __restrict__ thr_p,
               const float* __restrict__ epi_f32,
               const float* __restrict__ ms_p){
  constexpr int TW = 32 + 2*H, TH = 16 + 2*H, TP = TW*TH;
  constexpr int SSTAGE = 4*TP*16;
  constexpr int SEPI = (EPI<=1 && NH==2) ? 40960 : 0;
  constexpr int SBYTES = SSTAGE > SEPI ? SSTAGE : SEPI;
  __shared__ __align__(16) char smem[SBYTES];

  const int tx = blockIdx.x, ty = blockIdx.y, b = blockIdx.z;
  const int x0 = tx*32, y0 = ty*16;
  const int tid = threadIdx.x;
  const int lane = tid & 63, w = tid >> 6;
  const int m = lane & 15, q = lane >> 4;

  // ---- stage input tile (blocked 16B chunks), zero-pad, apply ITRANS ----
  float thr = (ITRANS==2) ? *thr_p : 0.f;
  uint4* sm16 = (uint4*)smem;
  for (int i = tid; i < 4*TP; i += 256){
    int g = i / TP; int rr = i - g*TP; int r = rr / TW; int c = rr - r*TW;
    int gy = y0 - H + r, gx = x0 - H + c;
    uint4 v = make_uint4(0,0,0,0);
    if (gy>=0 && gy<HW && gx>=0 && gx<HW)
      v = inb[(((size_t)(b*4+g)*HW + gy)*HW + gx)];
    if (ITRANS==1){
      unsigned* pw = (unsigned*)&v;
      #pragma unroll
      for (int z=0;z<4;z++){
        unsigned lo = pw[z] & 0xffffu, hi = pw[z] >> 16;
        if (lo & 0x8000u) lo = 0;
        if (hi & 0x8000u) hi = 0;
        pw[z] = lo | (hi<<16);
      }
    } else if (ITRANS==2){
      unsigned* pw = (unsigned*)&v;
      #pragma unroll
      for (int z=0;z<4;z++){
        unsigned lo = pw[z] & 0xffffu, hi = pw[z] >> 16;
        float f0 = __uint_as_float(lo<<16), f1 = __uint_as_float(hi<<16);
        float a0 = fabsf(f0)-thr, a1 = fabsf(f1)-thr;
        f0 = (a0>0.f)? copysignf(a0,f0) : 0.f;
        f1 = (a1>0.f)? copysignf(a1,f1) : 0.f;
        pw[z] = (unsigned)f2b(f0) | ((unsigned)f2b(f1)<<16);
      }
    }
    sm16[i] = v;
  }
  __syncthreads();

  // ---- K loop ----
  f32x4 acc[8][NH] = {};
  int pres = (NPASS==3) ? pres_p[set] : 2;
  for (int d = 1; d <= NPASS; ++d){
    if (NPASS==3 && !((pres>>d)&1)) continue;
    const uint4* wbase = wp + (size_t)(d-1)*1152;
    for (int t = 0; t < 9; ++t){
      int dy = (t/3 - 1)*d, dx = (t%3 - 1)*d;
      bf16x8 bfr[NH];
      #pragma unroll
      for (int h=0; h<NH; ++h)
        bfr[h] = __builtin_bit_cast(bf16x8, wbase[(h*9 + t)*64 + lane]);
      #pragma unroll
      for (int mt=0; mt<8; ++mt){
        int r = mt >> 1, xh = mt & 1;
        int lr = w*4 + r + H + dy;
        int lc = xh*16 + m + H + dx;
        bf16x8 a = __builtin_bit_cast(bf16x8, sm16[q*TP + lr*TW + lc]);
        #pragma unroll
        for (int h=0; h<NH; ++h)
          acc[mt][h] = __builtin_amdgcn_mfma_f32_16x16x32_bf16(a, bfr[h], acc[mt][h], 0,0,0);
      }
    }
  }

  // ---- epilogue ----
  if (EPI >= 2){
    float ms = (EPI==2) ? *ms_p : 0.f;
    #pragma unroll
    for (int mt=0; mt<8; ++mt){
      int r = mt >> 1, xh = mt & 1;
      int y = y0 + w*4 + r;
      int x = x0 + xh*16 + q*4;
      #pragma unroll
      for (int h=0; h<NH; ++h){
        int oc = h*16 + m;
        if (EPI==2){
          if (oc < 3){
            size_t off = (((size_t)(b*3+oc)*HW + y)*HW + x);
            float4 e = ld4(epi_f32 + off);
            float4 o;
            o.x = e.x + ms*acc[mt][h][0];
            o.y = e.y + ms*acc[mt][h][1];
            o.z = e.z + ms*acc[mt][h][2];
            o.w = e.w + ms*acc[mt][h][3];
            *reinterpret_cast<float4*>((float*)outp + off) = o;
          }
        } else {
          size_t off = (((size_t)(b*32+oc)*HW + y)*HW + x);
          float4 e = ld4(epi_f32 + off);
          float4 o;
          o.x = acc[mt][h][0] - e.x;
          o.y = acc[mt][h][1] - e.y;
          o.z = acc[mt][h][2] - e.z;
          o.w = acc[mt][h][3] - e.w;
          *reinterpret_cast<float4*>((float*)outp + off) = o;
        }
      }
    }
  } else {
    // blocked bf16 out via per-wave LDS transpose
    __syncthreads();
    short* sw = (short*)smem + (size_t)w*5120;     // [P][40 shorts] stride 80B
    #pragma unroll
    for (int mt=0; mt<8; ++mt){
      int r = mt >> 1, xh = mt & 1;
      #pragma unroll
      for (int h=0; h<NH; ++h){
        int oc = h*16 + m;
        #pragma unroll
        for (int reg=0; reg<4; ++reg){
          float v = acc[mt][h][reg];
          if (EPI==1) v = fmaxf(v, 0.f);
          int P = r*32 + xh*16 + q*4 + reg;
          sw[P*40 + oc] = (short)f2b(v);
        }
      }
    }
    // same-wave LDS is in-order; read back coalesced
    #pragma unroll
    for (int i=0;i<8;i++){
      int id = i*64 + lane;
      int g2 = id >> 7, P = id & 127;
      uint4 val = *reinterpret_cast<uint4*>(&sw[P*40 + g2*8]);
      int y2 = y0 + w*4 + (P>>5), x2 = x0 + (P&31);
      ((uint4*)outp)[(((size_t)(b*4+g2)*HW + y2)*HW + x2)] = val;
    }
  }
}

// ---------------------------------------------------------------------------
extern "C" void kernel_launch(void* const* d_in, const int* in_sizes, int n_in,
                              void* d_out, int out_size, void* d_ws, size_t ws_size,
                              hipStream_t stream) {
  const float* xprev = (const float*)d_in[0];
  const float* x     = (const float*)d_in[1];
  const float* PhiW  = (const float*)d_in[2];
  const float* PhiTW = (const float*)d_in[3];
  const float* PhiTb = (const float*)d_in[4];
  const float* lam   = (const float*)d_in[5];
  const float* sthr  = (const float*)d_in[6];
  const float* t_p   = (const float*)d_in[7];
  const float* mrg   = (const float*)d_in[8];
  const float* convD = (const float*)d_in[9];
  const float* conv3G= (const float*)d_in[10];
  const float* c1f_w=(const float*)d_in[11]; const float* c1f_p=(const float*)d_in[12];
  const float* c2f_w=(const float*)d_in[13]; const float* c2f_p=(const float*)d_in[14];
  const float* c1b_w=(const float*)d_in[15]; const float* c1b_p=(const float*)d_in[16];
  const float* c2b_w=(const float*)d_in[17]; const float* c2b_p=(const float*)d_in[18];
  const float* c1g_w=(const float*)d_in[19]; const float* c1g_p=(const float*)d_in[20];
  const float* c2g_w=(const float*)d_in[21]; const float* c2g_p=(const float*)d_in[22];

  char* ws = (char*)d_ws;
  const size_t BL = (size_t)NB*4*IMGSZ*16;          // blocked buffer 26,214,400 B
  uint4* xDb = (uint4*)(ws + 0*BL);
  uint4* Bb  = (uint4*)(ws + 1*BL);
  uint4* Cb  = (uint4*)(ws + 2*BL);
  uint4* Db  = (uint4*)(ws + 3*BL);
  uint4* Eb  = (uint4*)(ws + 4*BL);
  float* xDf = (float*)(ws + 5*BL);                 // 52,428,800
  float* x_input = (float*)(ws + 5*BL + 52428800);  // 4,915,200
  float* u       = (float*)(ws + 5*BL + 52428800 + 4915200);
  float* phi     = (float*)(ws + 5*BL + 52428800 + 2*4915200);
  uint4* Wp      = (uint4*)(ws + 5*BL + 52428800 + 3*4915200);   // 13*18432
  char*  mbase   = ws + 5*BL + 52428800 + 3*4915200 + 13*18432;
  int*   msrc    = (int*)(mbase);
  int*   md      = (int*)(mbase + 768);
  float* mscale  = (float*)(mbase + 2*768);
  int*   pres    = (int*)(mbase + 3*768);

  float* out0 = (float*)d_out;
  float* out1 = out0 + (size_t)NB*3*IMGSZ;

  // meta + weight packing
  meta_kernel<<<6, 64, 0, stream>>>(c1f_p,c2f_p,c1b_p,c2b_p,c1g_p,c2g_p,
                                    msrc, md, mscale, pres);
  pack_w<<<13, 256, 0, stream>>>(c1f_w,c2f_w,c1b_w,c2b_w,c1g_w,c2g_w,conv3G,
                                 msrc, md, mscale, Wp);

  // zeta path (fp32)
  ew_u<<<1200, 256, 0, stream>>>(x, xprev, t_p, u, 307200);
  phi_fwd<<<dim3(100,3,NB), 256, 0, stream>>>(u, PhiW, phi);
  phit_zeta<<<dim3(100,3,NB), 256, 0, stream>>>(phi, PhiTW, u, PhiTb, lam, x_input);

  // x_D = conv_D(x_input): direct fp32 -> NCHW, then convert to blocked bf16
  conv_direct<3,32,2,1><<<dim3(16,50,NB), dim3(16,16), 0, stream>>>(x_input, convD, xDf);
  cvt_blocked<<<6400, 256, 0, stream>>>(xDf, xDb);

  dim3 mg(10,20,NB);
  // slot bases (uint4 units of 1152 per slot)
  uint4* W_c1f = Wp + 0*1152;
  uint4* W_c2f = Wp + 1*1152;   // 3 classes
  uint4* W_c1b = Wp + 4*1152;
  uint4* W_c2b = Wp + 5*1152;   // 3 classes
  uint4* W_c1g = Wp + 8*1152;
  uint4* W_c2g = Wp + 9*1152;   // 3 classes
  uint4* W_g3  = Wp + 12*1152;

  // h1 = relu(adconv(x_D, c1f))
  mfma_conv<1,1,2,0,1><<<mg,256,0,stream>>>(xDb, W_c1f, Bb, nullptr,0, nullptr,nullptr,nullptr);
  // x_forward = adconv(h1, c2f)
  mfma_conv<3,3,2,0,0><<<mg,256,0,stream>>>(Bb, W_c2f, Cb, pres,1, nullptr,nullptr,nullptr);
  // h2 = relu(adconv(soft(x_forward), c1f))
  mfma_conv<1,1,2,2,1><<<mg,256,0,stream>>>(Cb, W_c1f, Db, nullptr,0, sthr,nullptr,nullptr);
  // x_backward = adconv(h2, c2b)
  mfma_conv<3,3,2,0,0><<<mg,256,0,stream>>>(Db, W_c2b, Eb, pres,3, nullptr,nullptr,nullptr);
  // h3 = adconv(relu(x_backward), c1g)
  mfma_conv<1,1,2,1,0><<<mg,256,0,stream>>>(Eb, W_c1g, Db, nullptr,0, nullptr,nullptr,nullptr);
  // h4 = adconv(relu(h3), c2g)
  mfma_conv<3,3,2,1,0><<<mg,256,0,stream>>>(Db, W_c2g, Eb, pres,5, nullptr,nullptr,nullptr);
  // x_pred = x_input + ms * conv3_G(h4)  -> out0
  mfma_conv<1,1,1,0,2><<<mg,256,0,stream>>>(Eb, W_g3, out0, nullptr,0, nullptr, x_input, mrg);
  // h5 = relu(adconv(x_forward, c1b))
  mfma_conv<1,1,2,0,1><<<mg,256,0,stream>>>(Cb, W_c1b, Db, nullptr,0, nullptr,nullptr,nullptr);
  // symloss = adconv(h5, c2b) - x_D  -> out1
  mfma_conv<3,3,2,0,3><<<mg,256,0,stream>>>(Db, W_c2b, out1, pres,3, nullptr, xDf, nullptr);
}